// Round 7
// baseline (275.287 us; speedup 1.0000x reference)
//
#include <hip/hip_runtime.h>
#include <hip/hip_bf16.h>
#include <stdint.h>

// MHA: B=1, L=4096, D=1024, H=16, dk=64.
// Inputs fp32, OUTPUT fp32. Internal compute bf16 with fp32 accumulation.
//
// Pipeline: cast -> gemm_qkv (epilogue writes frag-major Qt/Kt/Vt directly,
// Q pre-scaled by 0.125*log2e) -> flash v4 (K via LDS double-buffer, V direct
// from global/L1, S^T/O^T swap, max-free exp2 softmax) -> gemm O-proj.

typedef __bf16 bf16_t;
typedef __bf16 bf16x8 __attribute__((ext_vector_type(8)));
typedef __bf16 bf16x4 __attribute__((ext_vector_type(4)));
typedef float f32x4 __attribute__((ext_vector_type(4)));

#define MFMA_BF16 __builtin_amdgcn_mfma_f32_16x16x32_bf16

__device__ __forceinline__ void async_copy16(const void* g, void* lds) {
  __builtin_amdgcn_global_load_lds(
      (__attribute__((address_space(1))) void*)(uintptr_t)g,
      (__attribute__((address_space(3))) void*)lds, 16, 0, 0);
}

// ---------------------------------------------------------------------------
// fp32 -> bf16 cast, 8 elems/thread, z selects tensor.
// ---------------------------------------------------------------------------
__global__ __launch_bounds__(256) void cast_f32_bf16(
    const float* __restrict__ s0, bf16_t* __restrict__ d0, int n0,
    const float* __restrict__ s1, bf16_t* __restrict__ d1, int n1,
    const float* __restrict__ s2, bf16_t* __restrict__ d2, int n2,
    const float* __restrict__ s3, bf16_t* __restrict__ d3, int n3,
    const float* __restrict__ s4, bf16_t* __restrict__ d4, int n4,
    const float* __restrict__ s5, bf16_t* __restrict__ d5, int n5,
    const float* __restrict__ s6, bf16_t* __restrict__ d6, int n6) {
  const float* s;
  bf16_t* d;
  int n;
  switch (blockIdx.z) {
    case 0: s = s0; d = d0; n = n0; break;
    case 1: s = s1; d = d1; n = n1; break;
    case 2: s = s2; d = d2; n = n2; break;
    case 3: s = s3; d = d3; n = n3; break;
    case 4: s = s4; d = d4; n = n4; break;
    case 5: s = s5; d = d5; n = n5; break;
    default: s = s6; d = d6; n = n6; break;
  }
  const int i = (blockIdx.x * 256 + threadIdx.x) * 8;
  if (i >= n) return;
  float4 a = *(const float4*)(s + i);
  float4 b = *(const float4*)(s + i + 4);
  bf16x8 o;
  o[0] = (bf16_t)a.x; o[1] = (bf16_t)a.y; o[2] = (bf16_t)a.z; o[3] = (bf16_t)a.w;
  o[4] = (bf16_t)b.x; o[5] = (bf16_t)b.y; o[6] = (bf16_t)b.z; o[7] = (bf16_t)b.w;
  *(bf16x8*)(d + i) = o;
}

// ---------------------------------------------------------------------------
// QKV projection GEMM: C = A @ W^T + b, tile 128x128 BK=32 (m97 shape), but
// the epilogue writes directly into the frag-major tiled layouts:
//   z=0 -> Qt (scaled by 0.125*log2e), z=1 -> Kt  [row-tiles 16x64/head]
//   z=2 -> Vt [transposed tiles: 16 dk-rows x 64 kv]
// Tiled elem addr (Q/K):  h*262144 + (row>>4)*1024 + ((col>>5)&1)*512
//                        + ((col>>3)&3)*128 + (row&15)*8 + (col&7)
// Tiled elem addr (V):    h*262144 + ((row>>6)*4 + (dk>>4))*1024
//                        + ((row>>5)&1)*512 + ((row>>3)&3)*128
//                        + (dk&15)*8 + (row&7),  dk = col&63
// ---------------------------------------------------------------------------
__global__ __launch_bounds__(256) void gemm_qkv(
    const bf16_t* __restrict__ A0, const bf16_t* __restrict__ W0,
    const float* __restrict__ b0,
    const bf16_t* __restrict__ A1, const bf16_t* __restrict__ W1,
    const float* __restrict__ b1,
    const bf16_t* __restrict__ A2, const bf16_t* __restrict__ W2,
    const float* __restrict__ b2,
    bf16_t* __restrict__ Qt, bf16_t* __restrict__ Kt,
    bf16_t* __restrict__ Vt, int M, int N, int K) {
  const bf16_t *A, *W;
  const float* bias;
  bf16_t* C;
  const int z = blockIdx.z;
  if (z == 0)      { A = A0; W = W0; bias = b0; C = Qt; }
  else if (z == 1) { A = A1; W = W1; bias = b1; C = Kt; }
  else             { A = A2; W = W2; bias = b2; C = Vt; }

  __shared__ bf16_t As[128][32];
  __shared__ bf16_t Bs[128][32];

  const int t = threadIdx.x;
  const int w = t >> 6, lane = t & 63;
  const int quad = lane >> 4, l16 = lane & 15;
  const int wr = w >> 1, wc = w & 1;
  const int m0 = blockIdx.x * 128;
  const int n0 = blockIdx.y * 128;
  const int srow = lane >> 2;
  const int scol = (lane & 3) * 8;

  f32x4 acc[4][4] = {};

  for (int k0 = 0; k0 < K; k0 += 32) {
    async_copy16(&A[(size_t)(m0 + (2 * w) * 16 + srow) * K + k0 + scol],
                 (char*)As + (2 * w) * 1024);
    async_copy16(&A[(size_t)(m0 + (2 * w + 1) * 16 + srow) * K + k0 + scol],
                 (char*)As + (2 * w + 1) * 1024);
    async_copy16(&W[(size_t)(n0 + (2 * w) * 16 + srow) * K + k0 + scol],
                 (char*)Bs + (2 * w) * 1024);
    async_copy16(&W[(size_t)(n0 + (2 * w + 1) * 16 + srow) * K + k0 + scol],
                 (char*)Bs + (2 * w + 1) * 1024);
    __syncthreads();

    bf16x8 af[4], bfr[4];
#pragma unroll
    for (int mt = 0; mt < 4; mt++)
      af[mt] = *(const bf16x8*)&As[wr * 64 + mt * 16 + l16][quad * 8];
#pragma unroll
    for (int nt = 0; nt < 4; nt++)
      bfr[nt] = *(const bf16x8*)&Bs[wc * 64 + nt * 16 + l16][quad * 8];
#pragma unroll
    for (int mt = 0; mt < 4; mt++)
#pragma unroll
      for (int nt = 0; nt < 4; nt++)
        acc[mt][nt] = MFMA_BF16(af[mt], bfr[nt], acc[mt][nt], 0, 0, 0);
    __syncthreads();
  }

  if (z < 2) {
    const float scale = (z == 0) ? 0.125f * 1.44269504088896340736f : 1.0f;
#pragma unroll
    for (int nt = 0; nt < 4; nt++) {
      const int col = n0 + wc * 64 + nt * 16 + l16;
      const float bb = bias[col];
      const size_t base_nt = (size_t)(col >> 6) * 262144 +
                             ((col >> 5) & 1) * 512 + ((col >> 3) & 3) * 128 +
                             (col & 7);
#pragma unroll
      for (int mt = 0; mt < 4; mt++) {
        const int tile = (m0 >> 4) + wr * 4 + mt;
        const size_t tb = base_nt + (size_t)tile * 1024;
#pragma unroll
        for (int r = 0; r < 4; r++)
          C[tb + (quad * 4 + r) * 8] = (bf16_t)((acc[mt][nt][r] + bb) * scale);
      }
    }
  } else {
#pragma unroll
    for (int nt = 0; nt < 4; nt++) {
      const int col = n0 + wc * 64 + nt * 16 + l16;
      const int dk = col & 63;
      const float bb = bias[col];
      const size_t hb = (size_t)(col >> 6) * 262144 +
                        (size_t)(dk >> 4) * 1024 + (dk & 15) * 8;
#pragma unroll
      for (int mt = 0; mt < 4; mt++) {
        const int rb = m0 + wr * 64 + mt * 16 + quad * 4;  // kv row of r=0
        const size_t addr = hb + (size_t)(rb >> 6) * 4096 +
                            ((rb >> 5) & 1) * 512 + ((rb >> 3) & 3) * 128 +
                            (rb & 7);
        bf16x4 pk;
#pragma unroll
        for (int r = 0; r < 4; r++) pk[r] = (bf16_t)(acc[mt][nt][r] + bb);
        *(bf16x4*)&C[addr] = pk;
      }
    }
  }
}

// ---------------------------------------------------------------------------
// O-projection GEMM (standard row-major output, fp32).
// ---------------------------------------------------------------------------
__global__ __launch_bounds__(256) void gemm_out(
    const bf16_t* __restrict__ A, const bf16_t* __restrict__ W,
    const float* __restrict__ bias, float* __restrict__ C, int M, int N,
    int K) {
  __shared__ bf16_t As[128][32];
  __shared__ bf16_t Bs[128][32];

  const int t = threadIdx.x;
  const int w = t >> 6, lane = t & 63;
  const int quad = lane >> 4, l16 = lane & 15;
  const int wr = w >> 1, wc = w & 1;
  const int m0 = blockIdx.x * 128;
  const int n0 = blockIdx.y * 128;
  const int srow = lane >> 2;
  const int scol = (lane & 3) * 8;

  f32x4 acc[4][4] = {};

  for (int k0 = 0; k0 < K; k0 += 32) {
    async_copy16(&A[(size_t)(m0 + (2 * w) * 16 + srow) * K + k0 + scol],
                 (char*)As + (2 * w) * 1024);
    async_copy16(&A[(size_t)(m0 + (2 * w + 1) * 16 + srow) * K + k0 + scol],
                 (char*)As + (2 * w + 1) * 1024);
    async_copy16(&W[(size_t)(n0 + (2 * w) * 16 + srow) * K + k0 + scol],
                 (char*)Bs + (2 * w) * 1024);
    async_copy16(&W[(size_t)(n0 + (2 * w + 1) * 16 + srow) * K + k0 + scol],
                 (char*)Bs + (2 * w + 1) * 1024);
    __syncthreads();

    bf16x8 af[4], bfr[4];
#pragma unroll
    for (int mt = 0; mt < 4; mt++)
      af[mt] = *(const bf16x8*)&As[wr * 64 + mt * 16 + l16][quad * 8];
#pragma unroll
    for (int nt = 0; nt < 4; nt++)
      bfr[nt] = *(const bf16x8*)&Bs[wc * 64 + nt * 16 + l16][quad * 8];
#pragma unroll
    for (int mt = 0; mt < 4; mt++)
#pragma unroll
      for (int nt = 0; nt < 4; nt++)
        acc[mt][nt] = MFMA_BF16(af[mt], bfr[nt], acc[mt][nt], 0, 0, 0);
    __syncthreads();
  }

#pragma unroll
  for (int nt = 0; nt < 4; nt++) {
    const int col = n0 + wc * 64 + nt * 16 + l16;
    const float bb = bias[col];
#pragma unroll
    for (int mt = 0; mt < 4; mt++) {
#pragma unroll
      for (int r = 0; r < 4; r++) {
        const int row = m0 + wr * 64 + mt * 16 + quad * 4 + r;
        C[(size_t)row * N + col] = acc[mt][nt][r] + bb;
      }
    }
  }
}

// ---------------------------------------------------------------------------
// Flash v4.  Block = 4 waves x 32 q-rows = 128 q-rows, one head; full kv
// sweep per wave.  Per kv-chunk-64: K chunk (8 KB, contiguous frag-major)
// staged into double-buffered LDS via global_load_lds; V fragments loaded
// DIRECTLY global->VGPR (coalesced b128, shared across waves -> L1 hits),
// issued right after the barrier so S+softmax hides their latency.
// ---------------------------------------------------------------------------
__global__ __launch_bounds__(256, 2) void flash_attn(
    const bf16_t* __restrict__ Qt, const bf16_t* __restrict__ Kt,
    const bf16_t* __restrict__ Vt, bf16_t* __restrict__ O, int L) {
  const int h = blockIdx.y;
  const int t = threadIdx.x;
  const int w = t >> 6, lane = t & 63;
  const int quad = lane >> 4, l16 = lane & 15;
  const int tq0 = blockIdx.x * 8 + w * 2;  // wave owns q-tiles tq0, tq0+1

  __shared__ bf16_t Kst[2][4096];   // 8 KB per buffer
  __shared__ bf16_t Pb[4][32][72];  // per-wave P [q][kv+pad], 18.4 KB

  const size_t hb = (size_t)h * 262144;  // head base in tiled layouts

  // persistent Q B-frags (already scaled by 0.125*log2e in gemm_qkv)
  bf16x8 qa[2][2];
#pragma unroll
  for (int qt = 0; qt < 2; qt++)
#pragma unroll
    for (int kc = 0; kc < 2; kc++)
      qa[qt][kc] = *(const bf16x8*)(Qt + hb + (size_t)(tq0 + qt) * 1024 +
                                    kc * 512 + lane * 8);

#define STAGE(it_, buf_)                                                     \
  {                                                                          \
    const size_t cb = hb + (size_t)(it_) * 4096;                             \
    async_copy16(Kt + cb + (size_t)t * 8, (char*)&Kst[buf_][0] + w * 1024);  \
    async_copy16(Kt + cb + (size_t)(256 + t) * 8,                            \
                 (char*)&Kst[buf_][0] + 4096 + w * 1024);                    \
  }

  STAGE(0, 0);

  f32x4 oT[2][4] = {};   // [qt][dkt]
  float ls[2] = {0.f, 0.f};

  const int NIT = L / 64;  // 64
  for (int it = 0; it < NIT; it++) {
    const int buf = it & 1;
    __syncthreads();  // drains last iter's K copies; protects dbuf WAR
    if (it + 1 < NIT) STAGE(it + 1, buf ^ 1);

    // V A-frags direct from global (coalesced b128; consumed ~800cyc later)
    bf16x8 vb[4][2];
#pragma unroll
    for (int dkt = 0; dkt < 4; dkt++)
#pragma unroll
      for (int kvc = 0; kvc < 2; kvc++)
        vb[dkt][kvc] = *(const bf16x8*)(Vt + hb + (size_t)(it * 4 + dkt) * 1024 +
                                        kvc * 512 + lane * 8);

    // K frags from staged LDS (conflict-free b128)
    bf16x8 kb[4][2];
#pragma unroll
    for (int tt = 0; tt < 4; tt++)
#pragma unroll
      for (int kc = 0; kc < 2; kc++)
        kb[tt][kc] = *(const bf16x8*)((const char*)&Kst[buf][0] + tt * 2048 +
                                      kc * 1024 + lane * 16);

#pragma unroll
    for (int qt = 0; qt < 2; qt++) {
      // S^T tile column qt: lane = (q=l16, kv=quad*4+r+16tt)
      f32x4 sT[4];
#pragma unroll
      for (int tt = 0; tt < 4; tt++) {
        f32x4 z = {0.f, 0.f, 0.f, 0.f};
        z = MFMA_BF16(kb[tt][0], qa[qt][0], z, 0, 0, 0);
        z = MFMA_BF16(kb[tt][1], qa[qt][1], z, 0, 0, 0);
        sT[tt] = z;
      }
      // p = 2^s ; lsum ; pack 4 kv-consecutive bf16 -> one b64 LDS write
#pragma unroll
      for (int tt = 0; tt < 4; tt++) {
        bf16x4 pk;
        float rs = 0.f;
#pragma unroll
        for (int r = 0; r < 4; r++) {
          const float p = __builtin_amdgcn_exp2f(sT[tt][r]);
          rs += p;
          pk[r] = (bf16_t)p;
        }
        ls[qt] += rs;
        *(bf16x4*)&Pb[w][qt * 16 + l16][tt * 16 + quad * 4] = pk;
      }
    }

    // O^T += V^T . P  (wave-local LDS, in-order => no extra barrier)
#pragma unroll
    for (int qt = 0; qt < 2; qt++) {
      const bf16x8 pf0 = *(const bf16x8*)&Pb[w][qt * 16 + l16][quad * 8];
      const bf16x8 pf1 = *(const bf16x8*)&Pb[w][qt * 16 + l16][32 + quad * 8];
#pragma unroll
      for (int dkt = 0; dkt < 4; dkt++) {
        oT[qt][dkt] = MFMA_BF16(vb[dkt][0], pf0, oT[qt][dkt], 0, 0, 0);
        oT[qt][dkt] = MFMA_BF16(vb[dkt][1], pf1, oT[qt][dkt], 0, 0, 0);
      }
    }
  }
#undef STAGE

  // finalize: reduce ls across the 4 quads sharing each q-row; store O
#pragma unroll
  for (int qt = 0; qt < 2; qt++) {
    float l = ls[qt];
    l += __shfl_xor(l, 16);
    l += __shfl_xor(l, 32);
    const float inv = 1.0f / l;
    const size_t row = (size_t)(tq0 + qt) * 16 + l16;
#pragma unroll
    for (int dkt = 0; dkt < 4; dkt++)
#pragma unroll
      for (int r = 0; r < 4; r++)
        O[row * 1024 + h * 64 + dkt * 16 + quad * 4 + r] =
            (bf16_t)(oT[qt][dkt][r] * inv);
  }
}

// ---------------------------------------------------------------------------
extern "C" void kernel_launch(void* const* d_in, const int* in_sizes, int n_in,
                              void* d_out, int out_size, void* d_ws,
                              size_t ws_size, hipStream_t stream) {
  const float* q  = (const float*)d_in[0];
  const float* k  = (const float*)d_in[1];
  const float* v  = (const float*)d_in[2];
  const float* wq = (const float*)d_in[3];
  const float* bq = (const float*)d_in[4];
  const float* wk = (const float*)d_in[5];
  const float* bk = (const float*)d_in[6];
  const float* wv = (const float*)d_in[7];
  const float* bv = (const float*)d_in[8];
  const float* wo = (const float*)d_in[9];
  const float* bo = (const float*)d_in[10];
  float* out = (float*)d_out;

  const int L = 4096, D = 1024;
  const int nLD = L * D;  // 4M
  const int nDD = D * D;  // 1M
  bf16_t* p = (bf16_t*)d_ws;
  bf16_t* qb  = p; p += nLD;
  bf16_t* kb  = p; p += nLD;
  bf16_t* vb  = p; p += nLD;
  bf16_t* wqb = p; p += nDD;
  bf16_t* wkb = p; p += nDD;
  bf16_t* wvb = p; p += nDD;
  bf16_t* wob = p; p += nDD;
  bf16_t* Qt  = p; p += nLD;
  bf16_t* Kt  = p; p += nLD;
  bf16_t* Vt  = p; p += nLD;
  bf16_t* Op  = qb;  // reuse: qb consumed by gemm_qkv before flash writes Op

  dim3 blk(256);
  cast_f32_bf16<<<dim3(nLD / (256 * 8), 1, 7), blk, 0, stream>>>(
      q, qb, nLD, k, kb, nLD, v, vb, nLD, wq, wqb, nDD, wk, wkb, nDD,
      wv, wvb, nDD, wo, wob, nDD);
  gemm_qkv<<<dim3(L / 128, D / 128, 3), blk, 0, stream>>>(
      qb, wqb, bq, kb, wkb, bk, vb, wvb, bv, Qt, Kt, Vt, L, D, D);
  flash_attn<<<dim3(L / 128, 16), blk, 0, stream>>>(Qt, Kt, Vt, Op, L);
  gemm_out<<<dim3(L / 128, D / 128), blk, 0, stream>>>(Op, wob, bo, out, L, D,
                                                       D);
}